// Round 15
// baseline (731.876 us; speedup 1.0000x reference)
//
#include <hip/hip_runtime.h>
#include <math.h>

#define NSEG 533
#define CFEAT 2112
#define PIX 160000
#define SIM_THRESH 0.97f
#define RPG 1250            // 128-px rounds per ch-group
#define NCG 22              // ch-groups of 96
#define RTOT (RPG * NCG)    // 27500 round-tasks
#define NBLK 256            // 1 block/CU (16 waves)

typedef __attribute__((ext_vector_type(4))) float f32x4;
typedef __attribute__((ext_vector_type(4))) int   i32x4;
typedef __attribute__((ext_vector_type(8))) short bf16x8;

__device__ inline unsigned short f2bf_u16(float f) {
    unsigned u = __builtin_bit_cast(unsigned, f);
    return (unsigned short)((u + 0x7FFFu + ((u >> 16) & 1u)) >> 16);
}

// K1: per-segment label histogram, LDS-privatized (32 blocks x 5000 px)
__global__ __launch_bounds__(256) void k_counts(const int* __restrict__ sp,
                                                const int* __restrict__ y,
                                                int* __restrict__ c3) {
    __shared__ int h[NSEG * 3];
    for (int e = threadIdx.x; e < NSEG * 3; e += 256) h[e] = 0;
    __syncthreads();
    const int base = blockIdx.x * 5000;
    for (int p = threadIdx.x; p < 5000; p += 256) {
        int idx = base + p;
        atomicAdd(&h[sp[idx] * 3 + y[idx]], 1);
    }
    __syncthreads();
    for (int e = threadIdx.x; e < NSEG * 3; e += 256) {
        int v = h[e];
        if (v) atomicAdd(&c3[e], v);
    }
}

// K2: majority label + tie-break, writes lab/labeled outputs
__global__ __launch_bounds__(256) void k_labels(const int* __restrict__ c3,
                                                int* __restrict__ lab,
                                                float* __restrict__ invc,
                                                float* __restrict__ out) {
    int s = blockIdx.x * 256 + threadIdx.x;
    if (s >= NSEG) return;
    int c0 = c3[s * 3 + 0], c1 = c3[s * 3 + 1], c2 = c3[s * 3 + 2];
    int cnt = c0 + c1 + c2;
    int idx = 0, best = c0;
    if (c1 > best) { best = c1; idx = 1; }
    if (c2 > best) { best = c2; idx = 2; }
    if (idx == 0) idx = (c2 > c1) ? 2 : ((c1 > c2) ? 1 : 0);
    lab[s] = idx;
    invc[s] = 1.0f / (float)(cnt > 0 ? cnt : 1);
    out[1066 + s] = (float)idx;
    out[1599 + s] = (idx != 0) ? 1.0f : 0.0f;
}

// K3 v15: R12/R14 fp8 onehot-MFMA segsum, ch-group widened 64->96 (NCG 22):
// A-build VALU, sp-load duplication, and barrier count all drop 33%; LDS
// row stride stays 128 B (fp8) so the proven conflict-free pattern holds.
// 16 waves x 2 uniform tiles; tail tiles 32/33 as (tile,ks) units on waves
// 0..7 (R14 balance). Staging: 768 threads x 16 px, two 8-B XOR writes
// (same involution as reads). acc 72 AGPR; spill check via WRITE_SIZE.
__global__ __launch_bounds__(1024, 4) void k_segsum_mfma(const float* __restrict__ fm,
                                                         const int* __restrict__ sp,
                                                         float* __restrict__ sums) {
    __shared__ char Bs[2][96 * 128];   // 24 KB: 96 ch rows x 128 px fp8
    const int tid = threadIdx.x;
    const int lane = tid & 63, wave = tid >> 6;      // wave 0..15
    const int r = lane & 15, kg = lane >> 4;
    const int tgt0 = (wave * 2 + 0) * 16 + r;
    const int tgt1 = (wave * 2 + 1) * 16 + r;
    const bool tl = (wave < 8);                      // has a tail (tile,ks) unit
    const int ttile = 32 + (wave >= 4 ? 1 : 0);
    const int tgtT = ttile * 16 + r;
    const int tks = wave & 3;
    const int rswz = (r & 7) << 3;                   // read-side XOR (8B granule)
    const int sch = tid >> 3;                        // staging channel (use <96)
    const int spx = tid & 7;                         // staging 16-px chunk
    const bool stg = (sch < 96);
    const int wswz = (sch & 7) << 3;

    long long t0 = ((long long)blockIdx.x * RTOT) / NBLK;
    const long long t1 = ((long long)(blockIdx.x + 1) * RTOT) / NBLK;

    while (t0 < t1) {
        const int cg = (int)(t0 / RPG);
        const int r0 = (int)(t0 - (long long)cg * RPG);
        const long long cgend = (long long)(cg + 1) * RPG;
        const int rend = (int)(((t1 < cgend) ? t1 : cgend) - (long long)cg * RPG);
        const int c0 = cg * 96;
        const float* fmg = stg ? (fm + (size_t)(c0 + sch) * PIX + spx * 16) : fm;

        f32x4 acc0[6] = {}, acc1[6] = {}, accT[6] = {};

        // cvt 16 f32 -> 4 fp8-words, two 8-B writes (same XOR as reads)
        auto cvtWrite = [&](int buf, f32x4 u0, f32x4 u1, f32x4 u2, f32x4 u3) {
            if (!stg) return;
            int w0 = __builtin_amdgcn_cvt_pk_fp8_f32(u0[0], u0[1], 0, false);
            w0 = __builtin_amdgcn_cvt_pk_fp8_f32(u0[2], u0[3], w0, true);
            int w1 = __builtin_amdgcn_cvt_pk_fp8_f32(u1[0], u1[1], 0, false);
            w1 = __builtin_amdgcn_cvt_pk_fp8_f32(u1[2], u1[3], w1, true);
            int w2 = __builtin_amdgcn_cvt_pk_fp8_f32(u2[0], u2[1], 0, false);
            w2 = __builtin_amdgcn_cvt_pk_fp8_f32(u2[2], u2[3], w2, true);
            int w3 = __builtin_amdgcn_cvt_pk_fp8_f32(u3[0], u3[1], 0, false);
            w3 = __builtin_amdgcn_cvt_pk_fp8_f32(u3[2], u3[3], w3, true);
            char* dst = Bs[buf] + sch * 128;
            uint2 wa = { (unsigned)w0, (unsigned)w1 };
            uint2 wb = { (unsigned)w2, (unsigned)w3 };
            *(uint2*)(dst + ((spx * 16) ^ wswz)) = wa;
            *(uint2*)(dst + ((spx * 16 + 8) ^ wswz)) = wb;
        };

        {   // prologue: stage round r0
            f32x4 u0 = {}, u1 = {}, u2 = {}, u3 = {};
            if (stg) {
                const float* src = fmg + r0 * 128;
                u0 = *(const f32x4*)src;
                u1 = *(const f32x4*)(src + 4);
                u2 = *(const f32x4*)(src + 8);
                u3 = *(const f32x4*)(src + 12);
            }
            cvtWrite(r0 & 1, u0, u1, u2, u3);
        }
        __syncthreads();

        for (int rr = r0; rr < rend; ++rr) {
            const bool pf = (rr + 1 < rend);
            f32x4 u0 = {}, u1 = {}, u2 = {}, u3 = {};
            if (pf && stg) {   // issue next round's global loads early (T14)
                const float* src = fmg + (rr + 1) * 128;
                u0 = *(const f32x4*)src;
                u1 = *(const f32x4*)(src + 4);
                u2 = *(const f32x4*)(src + 8);
                u3 = *(const f32x4*)(src + 12);
            }
            const char* bufc = Bs[rr & 1];
            const int* spr = sp + rr * 128 + kg * 8;
            i32x4 sa = *(const i32x4*)spr;          // rolling sp prefetch
            i32x4 sb = *(const i32x4*)(spr + 4);

            #pragma unroll
            for (int ks = 0; ks < 4; ++ks) {
                i32x4 na, nb;
                if (ks < 3) {
                    na = *(const i32x4*)(spr + (ks + 1) * 32);
                    nb = *(const i32x4*)(spr + (ks + 1) * 32 + 4);
                }
                int seg[8] = { sa[0], sa[1], sa[2], sa[3], sb[0], sb[1], sb[2], sb[3] };
                // B fragments: b64 (8 fp8) per nt, proven conflict pattern
                uint2 vb[6];
                #pragma unroll
                for (int nt = 0; nt < 6; ++nt)
                    vb[nt] = *(const uint2*)(bufc + (nt * 16 + r) * 128 +
                                             ((ks * 32 + kg * 8) ^ rswz));

                // tile 0 (onehot A in fp8: 1.0 = 0x38 e4m3)
                {
                    unsigned a0 = ((seg[0] == tgt0) ? 0x38u : 0u) |
                                  ((seg[1] == tgt0) ? 0x3800u : 0u) |
                                  ((seg[2] == tgt0) ? 0x380000u : 0u) |
                                  ((seg[3] == tgt0) ? 0x38000000u : 0u);
                    unsigned a1 = ((seg[4] == tgt0) ? 0x38u : 0u) |
                                  ((seg[5] == tgt0) ? 0x3800u : 0u) |
                                  ((seg[6] == tgt0) ? 0x380000u : 0u) |
                                  ((seg[7] == tgt0) ? 0x38000000u : 0u);
                    if (__any((a0 | a1) != 0u)) {
                        long long av = __builtin_bit_cast(long long, (uint2){ a0, a1 });
                        #pragma unroll
                        for (int nt = 0; nt < 6; ++nt)
                            acc0[nt] = __builtin_amdgcn_mfma_f32_16x16x32_fp8_fp8(
                                av, __builtin_bit_cast(long long, vb[nt]), acc0[nt], 0, 0, 0);
                    }
                }
                // tile 1
                {
                    unsigned a0 = ((seg[0] == tgt1) ? 0x38u : 0u) |
                                  ((seg[1] == tgt1) ? 0x3800u : 0u) |
                                  ((seg[2] == tgt1) ? 0x380000u : 0u) |
                                  ((seg[3] == tgt1) ? 0x38000000u : 0u);
                    unsigned a1 = ((seg[4] == tgt1) ? 0x38u : 0u) |
                                  ((seg[5] == tgt1) ? 0x3800u : 0u) |
                                  ((seg[6] == tgt1) ? 0x380000u : 0u) |
                                  ((seg[7] == tgt1) ? 0x38000000u : 0u);
                    if (__any((a0 | a1) != 0u)) {
                        long long av = __builtin_bit_cast(long long, (uint2){ a0, a1 });
                        #pragma unroll
                        for (int nt = 0; nt < 6; ++nt)
                            acc1[nt] = __builtin_amdgcn_mfma_f32_16x16x32_fp8_fp8(
                                av, __builtin_bit_cast(long long, vb[nt]), acc1[nt], 0, 0, 0);
                    }
                }
                // tail unit: tile 32/33, this wave's ks only (wave-uniform)
                if (tl && ks == tks) {
                    unsigned a0 = ((seg[0] == tgtT) ? 0x38u : 0u) |
                                  ((seg[1] == tgtT) ? 0x3800u : 0u) |
                                  ((seg[2] == tgtT) ? 0x380000u : 0u) |
                                  ((seg[3] == tgtT) ? 0x38000000u : 0u);
                    unsigned a1 = ((seg[4] == tgtT) ? 0x38u : 0u) |
                                  ((seg[5] == tgtT) ? 0x3800u : 0u) |
                                  ((seg[6] == tgtT) ? 0x380000u : 0u) |
                                  ((seg[7] == tgtT) ? 0x38000000u : 0u);
                    if (__any((a0 | a1) != 0u)) {
                        long long av = __builtin_bit_cast(long long, (uint2){ a0, a1 });
                        #pragma unroll
                        for (int nt = 0; nt < 6; ++nt)
                            accT[nt] = __builtin_amdgcn_mfma_f32_16x16x32_fp8_fp8(
                                av, __builtin_bit_cast(long long, vb[nt]), accT[nt], 0, 0, 0);
                    }
                }
                if (ks < 3) { sa = na; sb = nb; }
            }

            if (pf) cvtWrite((rr + 1) & 1, u0, u1, u2, u3);
            __syncthreads();
        }

        // flush: C/D col(ch)=r, row(seg)=kg*4+q (rows 533..543 = zero pad)
        #pragma unroll
        for (int nt = 0; nt < 6; ++nt) {
            #pragma unroll
            for (int q = 0; q < 4; ++q) {
                int s0 = (wave * 2 + 0) * 16 + kg * 4 + q;
                int s1 = (wave * 2 + 1) * 16 + kg * 4 + q;
                unsafeAtomicAdd(&sums[(size_t)s0 * CFEAT + c0 + nt * 16 + r], acc0[nt][q]);
                unsafeAtomicAdd(&sums[(size_t)s1 * CFEAT + c0 + nt * 16 + r], acc1[nt][q]);
            }
        }
        if (tl) {
            #pragma unroll
            for (int nt = 0; nt < 6; ++nt) {
                #pragma unroll
                for (int q = 0; q < 4; ++q) {
                    int s = ttile * 16 + kg * 4 + q;
                    unsafeAtomicAdd(&sums[(size_t)s * CFEAT + c0 + nt * 16 + r], accT[nt][q]);
                }
            }
        }
        t0 = (t1 < cgend) ? t1 : cgend;
        if (t0 < t1) __syncthreads();   // LDS reuse across cg-chunks
    }
}

// K4: mean (in place) + bf16 copy + inverse row norm
__global__ __launch_bounds__(256) void k_mean(float* __restrict__ feat,
                                              unsigned short* __restrict__ featbf,
                                              const float* __restrict__ invc,
                                              float* __restrict__ invn) {
    int s = blockIdx.x;
    float ic = invc[s];
    float ss = 0.0f;
    for (int c = threadIdx.x; c < CFEAT; c += 256) {
        float v = feat[(size_t)s * CFEAT + c] * ic;
        feat[(size_t)s * CFEAT + c] = v;
        featbf[(size_t)s * CFEAT + c] = f2bf_u16(v);
        ss += v * v;
    }
    __shared__ float red[256];
    red[threadIdx.x] = ss;
    __syncthreads();
    for (int st = 128; st > 0; st >>= 1) {
        if (threadIdx.x < st) red[threadIdx.x] += red[threadIdx.x + st];
        __syncthreads();
    }
    if (threadIdx.x == 0) invn[s] = 1.0f / fmaxf(sqrtf(red[0]), 1e-12f);
}

// Fused transpose+cvt for all three weights in one launch.
__global__ __launch_bounds__(256) void k_cvtT_all(const float* __restrict__ w1,
                                                  const float* __restrict__ w2,
                                                  const float* __restrict__ w3,
                                                  unsigned short* __restrict__ w1T,
                                                  unsigned short* __restrict__ w2T,
                                                  unsigned short* __restrict__ w3T) {
    const float* in; unsigned short* outT; int K, N, k0;
    int yb = blockIdx.y;
    if (yb < 66)       { in = w1; outT = w1T; K = CFEAT; N = 1024; k0 = yb * 32; }
    else if (yb < 98)  { in = w2; outT = w2T; K = 1024;  N = 1024; k0 = (yb - 66) * 32; }
    else               { in = w3; outT = w3T; K = 1024;  N = 32;   k0 = (yb - 98) * 32;
                         if (blockIdx.x != 0) return; }
    __shared__ float s[32][33];
    int n0 = blockIdx.x * 32;
    int lx = threadIdx.x & 31, ly = threadIdx.x >> 5;   // ly 0..7
    #pragma unroll
    for (int p = 0; p < 4; ++p)
        s[ly + p * 8][lx] = in[(size_t)(k0 + ly + p * 8) * N + n0 + lx];
    __syncthreads();
    #pragma unroll
    for (int p = 0; p < 4; ++p)
        outT[(size_t)(n0 + ly + p * 8) * K + k0 + lx] = f2bf_u16(s[lx][ly + p * 8]);
}

// bf16 MFMA GEMM: C[M][N] = act(A[M][K] @ Bt[N][K]^T + bias).
template <int RELU>
__global__ __launch_bounds__(256) void gemm_bf16(const unsigned short* __restrict__ A,
                                                 const unsigned short* __restrict__ Bt,
                                                 const float* __restrict__ bias,
                                                 float* __restrict__ Cf,
                                                 unsigned short* __restrict__ Cb,
                                                 int M, int N, int K) {
    __shared__ char As[64 * 128];
    __shared__ char Bs[64 * 128];
    const int tid = threadIdx.x;
    const int lane = tid & 63, wave = tid >> 6;
    const int r = lane & 15, kg = lane >> 4;
    const int m0 = blockIdx.y * 64, n0 = blockIdx.x * 64;
    const int row = tid >> 2, colw = tid & 3;   // staging role
    const int swz = (row & 7) << 4;
    f32x4 acc[4] = {};

    for (int k0 = 0; k0 < K; k0 += 64) {
        {   // stage A (row-guarded)
            uint4 v0 = {}, v1 = {};
            if (m0 + row < M) {
                const unsigned short* src = A + (size_t)(m0 + row) * K + k0 + colw * 16;
                v0 = *(const uint4*)src;
                v1 = *(const uint4*)(src + 8);
            }
            *(uint4*)(As + row * 128 + ((colw * 32) ^ swz)) = v0;
            *(uint4*)(As + row * 128 + ((colw * 32 + 16) ^ swz)) = v1;
        }
        {   // stage Bt
            uint4 v0 = {}, v1 = {};
            if (n0 + row < N) {
                const unsigned short* src = Bt + (size_t)(n0 + row) * K + k0 + colw * 16;
                v0 = *(const uint4*)src;
                v1 = *(const uint4*)(src + 8);
            }
            *(uint4*)(Bs + row * 128 + ((colw * 32) ^ swz)) = v0;
            *(uint4*)(Bs + row * 128 + ((colw * 32 + 16) ^ swz)) = v1;
        }
        __syncthreads();
        #pragma unroll
        for (int ks = 0; ks < 2; ++ks) {
            const int arow = wave * 16 + r;
            bf16x8 va = *(const bf16x8*)(As + arow * 128 + (((ks * 64) + kg * 16) ^ ((arow & 7) << 4)));
            #pragma unroll
            for (int nt = 0; nt < 4; ++nt) {
                const int brow = nt * 16 + r;
                bf16x8 vb = *(const bf16x8*)(Bs + brow * 128 + (((ks * 64) + kg * 16) ^ ((brow & 7) << 4)));
                acc[nt] = __builtin_amdgcn_mfma_f32_16x16x32_bf16(va, vb, acc[nt], 0, 0, 0);
            }
        }
        __syncthreads();
    }

    #pragma unroll
    for (int nt = 0; nt < 4; ++nt) {
        #pragma unroll
        for (int q = 0; q < 4; ++q) {
            int gr = m0 + wave * 16 + kg * 4 + q;
            int gc = n0 + nt * 16 + r;
            if (gr < M && gc < N) {
                float v = acc[nt][q];
                if (bias) v += bias[gc];
                if (RELU) v = fmaxf(v, 0.0f);
                if (Cf) Cf[(size_t)gr * N + gc] = v;
                if (Cb) Cb[(size_t)gr * N + gc] = f2bf_u16(v);
            }
        }
    }
}

// K6: masked row-max/argmax over affinity + label propagation + fused head
__global__ __launch_bounds__(256) void k_prop(const float* __restrict__ aff,
                                              const int* __restrict__ lab,
                                              const float* __restrict__ invn,
                                              const float* __restrict__ h3,
                                              const float* __restrict__ wc,
                                              const float* __restrict__ bc,
                                              float* __restrict__ out) {
    int i = blockIdx.x;
    float invi = invn[i];
    float best = -INFINITY;
    int bidx = 0;
    for (int j = threadIdx.x; j < NSEG; j += 256) {
        if (lab[j] != 0) {
            float v = aff[(size_t)i * NSEG + j] * invi * invn[j];
            if (v > best) { best = v; bidx = j; }
        }
    }
    __shared__ float bv[256];
    __shared__ int bi[256];
    bv[threadIdx.x] = best;
    bi[threadIdx.x] = bidx;
    __syncthreads();
    for (int st = 128; st > 0; st >>= 1) {
        if (threadIdx.x < st) {
            float v2 = bv[threadIdx.x + st];
            int i2 = bi[threadIdx.x + st];
            if (v2 > bv[threadIdx.x] ||
                (v2 == bv[threadIdx.x] && i2 < bi[threadIdx.x])) {
                bv[threadIdx.x] = v2;
                bi[threadIdx.x] = i2;
            }
        }
        __syncthreads();
    }
    if (threadIdx.x == 0) {
        int li = lab[i];
        int nl = li;
        if (li == 0 && bv[0] >= SIM_THRESH) nl = lab[bi[0]];
        out[2132 + i] = (float)nl;
        float z0 = bc[0], z1 = bc[1];
        #pragma unroll
        for (int k = 0; k < 32; k++) {
            float h = h3[i * 32 + k];
            z0 += h * wc[k * 2 + 0];
            z1 += h * wc[k * 2 + 1];
        }
        float m = fmaxf(z0, z1);
        float e0 = expf(z0 - m), e1 = expf(z1 - m);
        float inv = 1.0f / (e0 + e1);
        out[i * 2 + 0] = e0 * inv;
        out[i * 2 + 1] = e1 * inv;
    }
}

extern "C" void kernel_launch(void* const* d_in, const int* in_sizes, int n_in,
                              void* d_out, int out_size, void* d_ws, size_t ws_size,
                              hipStream_t stream) {
    const float* fm = (const float*)d_in[0];
    const int* sp   = (const int*)d_in[1];
    const int* y    = (const int*)d_in[2];
    const float* w1 = (const float*)d_in[3];
    const float* b1 = (const float*)d_in[4];
    const float* w2 = (const float*)d_in[5];
    const float* b2 = (const float*)d_in[6];
    const float* w3 = (const float*)d_in[7];
    const float* b3 = (const float*)d_in[8];
    const float* wc = (const float*)d_in[9];
    const float* bc = (const float*)d_in[10];
    float* out = (float*)d_out;
    char* ws = (char*)d_ws;

    size_t off = 0;
    auto alloc = [&](size_t bytes) {
        size_t o = off;
        off += (bytes + 255) & ~(size_t)255;
        return o;
    };
    float*          feat   = (float*)(ws + alloc((size_t)544 * CFEAT * 4));
    unsigned short* featbf = (unsigned short*)(ws + alloc((size_t)544 * CFEAT * 2));
    unsigned short* w1T    = (unsigned short*)(ws + alloc((size_t)1024 * CFEAT * 2));
    unsigned short* w2T    = (unsigned short*)(ws + alloc((size_t)1024 * 1024 * 2));
    unsigned short* w3T    = (unsigned short*)(ws + alloc((size_t)32 * 1024 * 2));
    unsigned short* h1bf   = (unsigned short*)(ws + alloc((size_t)544 * 1024 * 2));
    unsigned short* h2bf   = (unsigned short*)(ws + alloc((size_t)544 * 1024 * 2));
    float*          h3     = (float*)(ws + alloc((size_t)544 * 32 * 4));
    float*          aff    = (float*)(ws + alloc((size_t)NSEG * NSEG * 4));
    int*            c3     = (int*)(ws + alloc((size_t)NSEG * 3 * 4));
    int*            lab    = (int*)(ws + alloc((size_t)NSEG * 4));
    float*          invc   = (float*)(ws + alloc((size_t)NSEG * 4));
    float*          invn   = (float*)(ws + alloc((size_t)NSEG * 4));

    hipMemsetAsync(feat, 0, (size_t)544 * CFEAT * 4, stream);
    hipMemsetAsync(c3, 0, (size_t)NSEG * 3 * 4, stream);

    k_cvtT_all<<<dim3(32, 130), 256, 0, stream>>>(w1, w2, w3, w1T, w2T, w3T);
    k_counts<<<32, 256, 0, stream>>>(sp, y, c3);
    k_labels<<<3, 256, 0, stream>>>(c3, lab, invc, out);
    k_segsum_mfma<<<NBLK, 1024, 0, stream>>>(fm, sp, feat);
    k_mean<<<NSEG, 256, 0, stream>>>(feat, featbf, invc, invn);

    gemm_bf16<1><<<dim3(16, 9), 256, 0, stream>>>(featbf, w1T, b1, nullptr, h1bf, NSEG, 1024, CFEAT);
    gemm_bf16<1><<<dim3(16, 9), 256, 0, stream>>>(h1bf, w2T, b2, nullptr, h2bf, NSEG, 1024, 1024);
    gemm_bf16<1><<<dim3(1, 9), 256, 0, stream>>>(h2bf, w3T, b3, h3, nullptr, NSEG, 32, 1024);
    gemm_bf16<0><<<dim3(9, 9), 256, 0, stream>>>(featbf, featbf, nullptr, aff, nullptr, NSEG, NSEG, CFEAT);

    k_prop<<<NSEG, 256, 0, stream>>>(aff, lab, invn, h3, wc, bc, out);
}

// Round 16
// 644.007 us; speedup vs baseline: 1.1364x; 1.1364x over previous
//
#include <hip/hip_runtime.h>
#include <math.h>

#define NSEG 533
#define CFEAT 2112
#define PIX 160000
#define SIM_THRESH 0.97f
#define RPG 1250            // 128-px rounds per ch-group
#define NCG 33              // ch-groups of 64
#define RTOT (RPG * NCG)    // 41250 round-tasks
#define NBLK 256            // 1 block/CU (16 waves)

typedef __attribute__((ext_vector_type(4))) float f32x4;
typedef __attribute__((ext_vector_type(4))) int   i32x4;
typedef __attribute__((ext_vector_type(8))) short bf16x8;

__device__ inline unsigned short f2bf_u16(float f) {
    unsigned u = __builtin_bit_cast(unsigned, f);
    return (unsigned short)((u + 0x7FFFu + ((u >> 16) & 1u)) >> 16);
}

// K1: per-segment label histogram, LDS-privatized (32 blocks x 5000 px)
__global__ __launch_bounds__(256) void k_counts(const int* __restrict__ sp,
                                                const int* __restrict__ y,
                                                int* __restrict__ c3) {
    __shared__ int h[NSEG * 3];
    for (int e = threadIdx.x; e < NSEG * 3; e += 256) h[e] = 0;
    __syncthreads();
    const int base = blockIdx.x * 5000;
    for (int p = threadIdx.x; p < 5000; p += 256) {
        int idx = base + p;
        atomicAdd(&h[sp[idx] * 3 + y[idx]], 1);
    }
    __syncthreads();
    for (int e = threadIdx.x; e < NSEG * 3; e += 256) {
        int v = h[e];
        if (v) atomicAdd(&c3[e], v);
    }
}

// K2: majority label + tie-break, writes lab/labeled outputs
__global__ __launch_bounds__(256) void k_labels(const int* __restrict__ c3,
                                                int* __restrict__ lab,
                                                float* __restrict__ invc,
                                                float* __restrict__ out) {
    int s = blockIdx.x * 256 + threadIdx.x;
    if (s >= NSEG) return;
    int c0 = c3[s * 3 + 0], c1 = c3[s * 3 + 1], c2 = c3[s * 3 + 2];
    int cnt = c0 + c1 + c2;
    int idx = 0, best = c0;
    if (c1 > best) { best = c1; idx = 1; }
    if (c2 > best) { best = c2; idx = 2; }
    if (idx == 0) idx = (c2 > c1) ? 2 : ((c1 > c2) ? 1 : 0);
    lab[s] = idx;
    invc[s] = 1.0f / (float)(cnt > 0 ? cnt : 1);
    out[1066 + s] = (float)idx;
    out[1599 + s] = (idx != 0) ? 1.0f : 0.0f;
}

// K3 v12 (FINAL, best-known): onehot-MFMA segsum in FP8 (e4m3).
// 16 waves, 64 ch, 2-buffer LDS, tiles built once (waves 0,1 own 3 incl
// 32/33; waves 2-15 own 2). fp8 operands: half LDS bytes (b64 frags,
// 16 KB LDS), half pack VALU (cvt_pk_fp8_f32), same MFMA rate as bf16.
// Ballot-skip: 37.7% of (tile,ks) windows have no matching pixel.
// fm read exactly once; rolling sp prefetch; atomic f32 flush.
// Search ledger (R5-R15): occupancy/pipeline-depth/round-size/LDS-bytes/
// tail-path/wave-balance/K=128/ch-width all falsified or regressions;
// this config is the empirical optimum of the decomposition.
__global__ __launch_bounds__(1024, 4) void k_segsum_mfma(const float* __restrict__ fm,
                                                         const int* __restrict__ sp,
                                                         float* __restrict__ sums) {
    __shared__ char Bs[2][64 * 128];   // 16 KB: 64 ch rows x 128 px fp8
    const int tid = threadIdx.x;
    const int lane = tid & 63, wave = tid >> 6;      // wave 0..15
    const int r = lane & 15, kg = lane >> 4;
    const int nmt = (wave < 2) ? 3 : 2;              // tiles {2w,2w+1} (+32+w for w<2)
    const int rswz = (r & 7) << 3;                   // read-side XOR (8B granule)
    const int sch = tid >> 4;                        // staging channel 0..63
    const int spx = tid & 15;                        // staging 8-px chunk
    const int wswz = (sch & 7) << 3;

    long long t0 = ((long long)blockIdx.x * RTOT) / NBLK;
    const long long t1 = ((long long)(blockIdx.x + 1) * RTOT) / NBLK;

    while (t0 < t1) {
        const int cg = (int)(t0 / RPG);
        const int r0 = (int)(t0 - (long long)cg * RPG);
        const long long cgend = (long long)(cg + 1) * RPG;
        const int rend = (int)(((t1 < cgend) ? t1 : cgend) - (long long)cg * RPG);
        const int c0 = cg * 64;
        const float* fmg = fm + (size_t)(c0 + sch) * PIX + spx * 8;

        f32x4 acc[3][4] = {};

        // load 8 px f32, cvt to 8 fp8 (2 words), write b64 to Bs[rr&1]
        auto stage = [&](int rr) {
            const float* src = fmg + rr * 128;
            f32x4 u0 = *(const f32x4*)src;
            f32x4 u1 = *(const f32x4*)(src + 4);
            int w0 = __builtin_amdgcn_cvt_pk_fp8_f32(u0[0], u0[1], 0, false);
            w0 = __builtin_amdgcn_cvt_pk_fp8_f32(u0[2], u0[3], w0, true);
            int w1 = __builtin_amdgcn_cvt_pk_fp8_f32(u1[0], u1[1], 0, false);
            w1 = __builtin_amdgcn_cvt_pk_fp8_f32(u1[2], u1[3], w1, true);
            uint2 w = { (unsigned)w0, (unsigned)w1 };
            *(uint2*)(Bs[rr & 1] + sch * 128 + ((spx * 8) ^ wswz)) = w;
        };

        stage(r0);
        __syncthreads();

        for (int rr = r0; rr < rend; ++rr) {
            const bool pf = (rr + 1 < rend);
            f32x4 u0 = {}, u1 = {};
            if (pf) {   // issue next round's global loads early (T14)
                const float* src = fmg + (rr + 1) * 128;
                u0 = *(const f32x4*)src;
                u1 = *(const f32x4*)(src + 4);
            }
            const char* bufc = Bs[rr & 1];
            const int* spr = sp + rr * 128 + kg * 8;
            i32x4 sa = *(const i32x4*)spr;          // rolling sp prefetch
            i32x4 sb = *(const i32x4*)(spr + 4);

            #pragma unroll
            for (int ks = 0; ks < 4; ++ks) {
                i32x4 na, nb;
                if (ks < 3) {
                    na = *(const i32x4*)(spr + (ks + 1) * 32);
                    nb = *(const i32x4*)(spr + (ks + 1) * 32 + 4);
                }
                int seg[8] = { sa[0], sa[1], sa[2], sa[3], sb[0], sb[1], sb[2], sb[3] };
                // B fragments: b64 (8 fp8) per nt, 2-way-conflict-free pattern
                uint2 vb[4];
                #pragma unroll
                for (int nt = 0; nt < 4; ++nt)
                    vb[nt] = *(const uint2*)(bufc + (nt * 16 + r) * 128 +
                                             ((ks * 32 + kg * 8) ^ rswz));
                #pragma unroll
                for (int i = 0; i < 3; ++i) {
                    if (i < nmt) {
                        const int tm = (i < 2) ? wave * 2 + i : 32 + wave;
                        const int tgt = tm * 16 + r;
                        // onehot A in fp8: 1.0 = 0x38 (e4m3), 4 px per word
                        unsigned a0 = ((seg[0] == tgt) ? 0x38u : 0u) |
                                      ((seg[1] == tgt) ? 0x3800u : 0u) |
                                      ((seg[2] == tgt) ? 0x380000u : 0u) |
                                      ((seg[3] == tgt) ? 0x38000000u : 0u);
                        unsigned a1 = ((seg[4] == tgt) ? 0x38u : 0u) |
                                      ((seg[5] == tgt) ? 0x3800u : 0u) |
                                      ((seg[6] == tgt) ? 0x380000u : 0u) |
                                      ((seg[7] == tgt) ? 0x3800u * 0x10000u : 0u);
                        // ballot-skip: 37.7% of (tile,ks) windows are all-zero
                        if (__any((a0 | a1) != 0u)) {
                            long long av = __builtin_bit_cast(long long, (uint2){ a0, a1 });
                            acc[i][0] = __builtin_amdgcn_mfma_f32_16x16x32_fp8_fp8(
                                av, __builtin_bit_cast(long long, vb[0]), acc[i][0], 0, 0, 0);
                            acc[i][1] = __builtin_amdgcn_mfma_f32_16x16x32_fp8_fp8(
                                av, __builtin_bit_cast(long long, vb[1]), acc[i][1], 0, 0, 0);
                            acc[i][2] = __builtin_amdgcn_mfma_f32_16x16x32_fp8_fp8(
                                av, __builtin_bit_cast(long long, vb[2]), acc[i][2], 0, 0, 0);
                            acc[i][3] = __builtin_amdgcn_mfma_f32_16x16x32_fp8_fp8(
                                av, __builtin_bit_cast(long long, vb[3]), acc[i][3], 0, 0, 0);
                        }
                    }
                }
                if (ks < 3) { sa = na; sb = nb; }
            }

            if (pf) {   // pack + write next round's buffer
                int w0 = __builtin_amdgcn_cvt_pk_fp8_f32(u0[0], u0[1], 0, false);
                w0 = __builtin_amdgcn_cvt_pk_fp8_f32(u0[2], u0[3], w0, true);
                int w1 = __builtin_amdgcn_cvt_pk_fp8_f32(u1[0], u1[1], 0, false);
                w1 = __builtin_amdgcn_cvt_pk_fp8_f32(u1[2], u1[3], w1, true);
                uint2 w = { (unsigned)w0, (unsigned)w1 };
                *(uint2*)(Bs[(rr + 1) & 1] + sch * 128 + ((spx * 8) ^ wswz)) = w;
            }
            __syncthreads();
        }

        // flush: C/D col(ch)=r, row(seg)=kg*4+q (rows 533..543 = zero pad)
        #pragma unroll
        for (int i = 0; i < 3; ++i) {
            if (i < nmt) {
                const int tm = (i < 2) ? wave * 2 + i : 32 + wave;
                #pragma unroll
                for (int nt = 0; nt < 4; ++nt) {
                    #pragma unroll
                    for (int q = 0; q < 4; ++q) {
                        int s = tm * 16 + kg * 4 + q;
                        unsafeAtomicAdd(&sums[(size_t)s * CFEAT + c0 + nt * 16 + r],
                                        acc[i][nt][q]);
                    }
                }
            }
        }
        t0 = (t1 < cgend) ? t1 : cgend;
        if (t0 < t1) __syncthreads();   // LDS reuse across cg-chunks
    }
}

// K4: mean (in place) + bf16 copy + inverse row norm
__global__ __launch_bounds__(256) void k_mean(float* __restrict__ feat,
                                              unsigned short* __restrict__ featbf,
                                              const float* __restrict__ invc,
                                              float* __restrict__ invn) {
    int s = blockIdx.x;
    float ic = invc[s];
    float ss = 0.0f;
    for (int c = threadIdx.x; c < CFEAT; c += 256) {
        float v = feat[(size_t)s * CFEAT + c] * ic;
        feat[(size_t)s * CFEAT + c] = v;
        featbf[(size_t)s * CFEAT + c] = f2bf_u16(v);
        ss += v * v;
    }
    __shared__ float red[256];
    red[threadIdx.x] = ss;
    __syncthreads();
    for (int st = 128; st > 0; st >>= 1) {
        if (threadIdx.x < st) red[threadIdx.x] += red[threadIdx.x + st];
        __syncthreads();
    }
    if (threadIdx.x == 0) invn[s] = 1.0f / fmaxf(sqrtf(red[0]), 1e-12f);
}

// Fused transpose+cvt for all three weights in one launch.
// grid(32, 130): y<66 -> w1 (K=2112,N=1024); 66..97 -> w2 (K=1024,N=1024);
// y>=98 -> w3 (K=1024,N=32, x==0 only).
__global__ __launch_bounds__(256) void k_cvtT_all(const float* __restrict__ w1,
                                                  const float* __restrict__ w2,
                                                  const float* __restrict__ w3,
                                                  unsigned short* __restrict__ w1T,
                                                  unsigned short* __restrict__ w2T,
                                                  unsigned short* __restrict__ w3T) {
    const float* in; unsigned short* outT; int K, N, k0;
    int yb = blockIdx.y;
    if (yb < 66)       { in = w1; outT = w1T; K = CFEAT; N = 1024; k0 = yb * 32; }
    else if (yb < 98)  { in = w2; outT = w2T; K = 1024;  N = 1024; k0 = (yb - 66) * 32; }
    else               { in = w3; outT = w3T; K = 1024;  N = 32;   k0 = (yb - 98) * 32;
                         if (blockIdx.x != 0) return; }
    __shared__ float s[32][33];
    int n0 = blockIdx.x * 32;
    int lx = threadIdx.x & 31, ly = threadIdx.x >> 5;   // ly 0..7
    #pragma unroll
    for (int p = 0; p < 4; ++p)
        s[ly + p * 8][lx] = in[(size_t)(k0 + ly + p * 8) * N + n0 + lx];
    __syncthreads();
    #pragma unroll
    for (int p = 0; p < 4; ++p)
        outT[(size_t)(n0 + ly + p * 8) * K + k0 + lx] = f2bf_u16(s[lx][ly + p * 8]);
}

// bf16 MFMA GEMM: C[M][N] = act(A[M][K] @ Bt[N][K]^T + bias).
// 64x64 tile, BK=64, 4 waves (wave = M-quarter). XOR-swizzled LDS.
template <int RELU>
__global__ __launch_bounds__(256) void gemm_bf16(const unsigned short* __restrict__ A,
                                                 const unsigned short* __restrict__ Bt,
                                                 const float* __restrict__ bias,
                                                 float* __restrict__ Cf,
                                                 unsigned short* __restrict__ Cb,
                                                 int M, int N, int K) {
    __shared__ char As[64 * 128];
    __shared__ char Bs[64 * 128];
    const int tid = threadIdx.x;
    const int lane = tid & 63, wave = tid >> 6;
    const int r = lane & 15, kg = lane >> 4;
    const int m0 = blockIdx.y * 64, n0 = blockIdx.x * 64;
    const int row = tid >> 2, colw = tid & 3;   // staging role
    const int swz = (row & 7) << 4;
    f32x4 acc[4] = {};

    for (int k0 = 0; k0 < K; k0 += 64) {
        {   // stage A (row-guarded)
            uint4 v0 = {}, v1 = {};
            if (m0 + row < M) {
                const unsigned short* src = A + (size_t)(m0 + row) * K + k0 + colw * 16;
                v0 = *(const uint4*)src;
                v1 = *(const uint4*)(src + 8);
            }
            *(uint4*)(As + row * 128 + ((colw * 32) ^ swz)) = v0;
            *(uint4*)(As + row * 128 + ((colw * 32 + 16) ^ swz)) = v1;
        }
        {   // stage Bt
            uint4 v0 = {}, v1 = {};
            if (n0 + row < N) {
                const unsigned short* src = Bt + (size_t)(n0 + row) * K + k0 + colw * 16;
                v0 = *(const uint4*)src;
                v1 = *(const uint4*)(src + 8);
            }
            *(uint4*)(Bs + row * 128 + ((colw * 32) ^ swz)) = v0;
            *(uint4*)(Bs + row * 128 + ((colw * 32 + 16) ^ swz)) = v1;
        }
        __syncthreads();
        #pragma unroll
        for (int ks = 0; ks < 2; ++ks) {
            const int arow = wave * 16 + r;
            bf16x8 va = *(const bf16x8*)(As + arow * 128 + (((ks * 64) + kg * 16) ^ ((arow & 7) << 4)));
            #pragma unroll
            for (int nt = 0; nt < 4; ++nt) {
                const int brow = nt * 16 + r;
                bf16x8 vb = *(const bf16x8*)(Bs + brow * 128 + (((ks * 64) + kg * 16) ^ ((brow & 7) << 4)));
                acc[nt] = __builtin_amdgcn_mfma_f32_16x16x32_bf16(va, vb, acc[nt], 0, 0, 0);
            }
        }
        __syncthreads();
    }

    #pragma unroll
    for (int nt = 0; nt < 4; ++nt) {
        #pragma unroll
        for (int q = 0; q < 4; ++q) {
            int gr = m0 + wave * 16 + kg * 4 + q;
            int gc = n0 + nt * 16 + r;
            if (gr < M && gc < N) {
                float v = acc[nt][q];
                if (bias) v += bias[gc];
                if (RELU) v = fmaxf(v, 0.0f);
                if (Cf) Cf[(size_t)gr * N + gc] = v;
                if (Cb) Cb[(size_t)gr * N + gc] = f2bf_u16(v);
            }
        }
    }
}

// K6: masked row-max/argmax over affinity + label propagation + fused head
__global__ __launch_bounds__(256) void k_prop(const float* __restrict__ aff,
                                              const int* __restrict__ lab,
                                              const float* __restrict__ invn,
                                              const float* __restrict__ h3,
                                              const float* __restrict__ wc,
                                              const float* __restrict__ bc,
                                              float* __restrict__ out) {
    int i = blockIdx.x;
    float invi = invn[i];
    float best = -INFINITY;
    int bidx = 0;
    for (int j = threadIdx.x; j < NSEG; j += 256) {
        if (lab[j] != 0) {
            float v = aff[(size_t)i * NSEG + j] * invi * invn[j];
            if (v > best) { best = v; bidx = j; }
        }
    }
    __shared__ float bv[256];
    __shared__ int bi[256];
    bv[threadIdx.x] = best;
    bi[threadIdx.x] = bidx;
    __syncthreads();
    for (int st = 128; st > 0; st >>= 1) {
        if (threadIdx.x < st) {
            float v2 = bv[threadIdx.x + st];
            int i2 = bi[threadIdx.x + st];
            if (v2 > bv[threadIdx.x] ||
                (v2 == bv[threadIdx.x] && i2 < bi[threadIdx.x])) {
                bv[threadIdx.x] = v2;
                bi[threadIdx.x] = i2;
            }
        }
        __syncthreads();
    }
    if (threadIdx.x == 0) {
        int li = lab[i];
        int nl = li;
        if (li == 0 && bv[0] >= SIM_THRESH) nl = lab[bi[0]];
        out[2132 + i] = (float)nl;
        float z0 = bc[0], z1 = bc[1];
        #pragma unroll
        for (int k = 0; k < 32; k++) {
            float h = h3[i * 32 + k];
            z0 += h * wc[k * 2 + 0];
            z1 += h * wc[k * 2 + 1];
        }
        float m = fmaxf(z0, z1);
        float e0 = expf(z0 - m), e1 = expf(z1 - m);
        float inv = 1.0f / (e0 + e1);
        out[i * 2 + 0] = e0 * inv;
        out[i * 2 + 1] = e1 * inv;
    }
}

extern "C" void kernel_launch(void* const* d_in, const int* in_sizes, int n_in,
                              void* d_out, int out_size, void* d_ws, size_t ws_size,
                              hipStream_t stream) {
    const float* fm = (const float*)d_in[0];
    const int* sp   = (const int*)d_in[1];
    const int* y    = (const int*)d_in[2];
    const float* w1 = (const float*)d_in[3];
    const float* b1 = (const float*)d_in[4];
    const float* w2 = (const float*)d_in[5];
    const float* b2 = (const float*)d_in[6];
    const float* w3 = (const float*)d_in[7];
    const float* b3 = (const float*)d_in[8];
    const float* wc = (const float*)d_in[9];
    const float* bc = (const float*)d_in[10];
    float* out = (float*)d_out;
    char* ws = (char*)d_ws;

    size_t off = 0;
    auto alloc = [&](size_t bytes) {
        size_t o = off;
        off += (bytes + 255) & ~(size_t)255;
        return o;
    };
    float*          feat   = (float*)(ws + alloc((size_t)544 * CFEAT * 4));
    unsigned short* featbf = (unsigned short*)(ws + alloc((size_t)544 * CFEAT * 2));
    unsigned short* w1T    = (unsigned short*)(ws + alloc((size_t)1024 * CFEAT * 2));
    unsigned short* w2T    = (unsigned short*)(ws + alloc((size_t)1024 * 1024 * 2));
    unsigned short* w3T    = (unsigned short*)(ws + alloc((size_t)32 * 1024 * 2));
    unsigned short* h1bf   = (unsigned short*)(ws + alloc((size_t)544 * 1024 * 2));
    unsigned short* h2bf   = (unsigned short*)(ws + alloc((size_t)544 * 1024 * 2));
    float*          h3     = (float*)(ws + alloc((size_t)544 * 32 * 4));
    float*          aff    = (float*)(ws + alloc((size_t)NSEG * NSEG * 4));
    int*            c3     = (int*)(ws + alloc((size_t)NSEG * 3 * 4));
    int*            lab    = (int*)(ws + alloc((size_t)NSEG * 4));
    float*          invc   = (float*)(ws + alloc((size_t)NSEG * 4));
    float*          invn   = (float*)(ws + alloc((size_t)NSEG * 4));

    hipMemsetAsync(feat, 0, (size_t)544 * CFEAT * 4, stream);
    hipMemsetAsync(c3, 0, (size_t)NSEG * 3 * 4, stream);

    k_cvtT_all<<<dim3(32, 130), 256, 0, stream>>>(w1, w2, w3, w1T, w2T, w3T);
    k_counts<<<32, 256, 0, stream>>>(sp, y, c3);
    k_labels<<<3, 256, 0, stream>>>(c3, lab, invc, out);
    k_segsum_mfma<<<NBLK, 1024, 0, stream>>>(fm, sp, feat);
    k_mean<<<NSEG, 256, 0, stream>>>(feat, featbf, invc, invn);

    gemm_bf16<1><<<dim3(16, 9), 256, 0, stream>>>(featbf, w1T, b1, nullptr, h1bf, NSEG, 1024, CFEAT);
    gemm_bf16<1><<<dim3(16, 9), 256, 0, stream>>>(h1bf, w2T, b2, nullptr, h2bf, NSEG, 1024, 1024);
    gemm_bf16<1><<<dim3(1, 9), 256, 0, stream>>>(h2bf, w3T, b3, h3, nullptr, NSEG, 32, 1024);
    gemm_bf16<0><<<dim3(9, 9), 256, 0, stream>>>(featbf, featbf, nullptr, aff, nullptr, NSEG, NSEG, CFEAT);

    k_prop<<<NSEG, 256, 0, stream>>>(aff, lab, invn, h3, wc, bc, out);
}